// Round 7
// baseline (515.766 us; speedup 1.0000x reference)
//
#include <hip/hip_runtime.h>

// Problem constants
#define BB      16384
#define IN_DIM  256
#define NE      32
#define H1D     64
#define H2D     256
#define H3D     128
#define NOUT    128

typedef __bf16 bf16_t;
typedef __bf16 bf16x8  __attribute__((ext_vector_type(8)));
typedef float  f32x4   __attribute__((ext_vector_type(4)));
typedef float  f32x16  __attribute__((ext_vector_type(16)));

// ---- workspace layout (bytes) ---- (total 15,810,560 B — within the proven r1–r5 budget)
// Wswz: [E][81920] bf16 — frag-linear weights, order L1,L2,L3,L4,L5
// bswz: [E][640]  fp32 — frag-order biases, 20 n-tiles x [half][reg]
// xswz: [512 bt][16 kc][64 lane][8] bf16
// gT:   [E][B] fp32
#define OFF_WS  ((size_t)0)
#define OFF_BS  (OFF_WS + (size_t)NE*81920*2)            //  5242880
#define OFF_XS  (OFF_BS + (size_t)NE*640*4)              //  5324800
#define OFF_GT  (OFF_XS + (size_t)BB*IN_DIM*2)           // 13713408

// ---- prep: weights+biases -> frag-linear swizzled bf16 ----
// Wswz elem ((nt*KC + kc)*64 + lane)*8 + j = W[k=kc*16+(lane>>5)*8+j][n=nt*32+(lane&31)]
__global__ void prep_w(const float* __restrict__ W1, const float* __restrict__ W2,
                       const float* __restrict__ W3, const float* __restrict__ W4,
                       const float* __restrict__ W5,
                       const float* __restrict__ b1, const float* __restrict__ b2,
                       const float* __restrict__ b3, const float* __restrict__ b4,
                       const float* __restrict__ b5,
                       bf16_t* __restrict__ Wswz, float* __restrict__ bswz)
{
    const int e   = blockIdx.x / 41;
    const int q   = blockIdx.x % 41;
    const int tid = threadIdx.x;

    if (q == 40) {  // biases: 20 n-tiles x 32 (=[half][reg]) fp32
        for (int idx = tid; idx < 640; idx += 256) {
            const int ntc = idx >> 5;
            const int s   = idx & 31;
            const int h   = s >> 4, r = s & 15;
            const int fo  = (r & 3) + 8 * (r >> 2) + 4 * h;
            const float* bp; int off;
            if (ntc < 2)       { bp = b1 + e * H1D;  off = ntc * 32; }
            else if (ntc < 10) { bp = b2 + e * H2D;  off = (ntc - 2) * 32; }
            else if (ntc < 14) { bp = b3 + e * H3D;  off = (ntc - 10) * 32; }
            else if (ntc < 16) { bp = b4 + e * H1D;  off = (ntc - 14) * 32; }
            else               { bp = b5 + e * NOUT; off = (ntc - 16) * 32; }
            bswz[(size_t)e * 640 + idx] = bp[off + fo];
        }
        return;
    }

    const float* W; int K, N, nt, kt, base;
    if (q < 8)       { W = W1; K = 256; N = 64;  nt = q >> 2;        kt = q & 3;        base = 0; }
    else if (q < 16) { W = W2; K = 64;  N = 256; nt = q - 8;         kt = 0;            base = 16384; }
    else if (q < 32) { W = W3; K = 256; N = 128; nt = (q - 16) >> 2; kt = (q - 16) & 3; base = 32768; }
    else if (q < 36) { W = W4; K = 128; N = 64;  nt = (q - 32) >> 1; kt = (q - 32) & 1; base = 65536; }
    else             { W = W5; K = 64;  N = 128; nt = q - 36;        kt = 0;            base = 73728; }
    const int KC = K / 16;

    __shared__ float tile[64][36];
    const float* src = W + (size_t)e * K * N;
    {
        const int row = tid >> 2;
        const int c0  = (tid & 3) * 8;
        const float* sp = src + (size_t)(kt * 64 + row) * N + nt * 32 + c0;
        *(float4*)&tile[row][c0]     = *(const float4*)sp;
        *(float4*)&tile[row][c0 + 4] = *(const float4*)(sp + 4);
    }
    __syncthreads();
    {
        const int kc2  = tid >> 6;            // 4 kc per 64-k tile
        const int l    = tid & 63;
        const int krow = kc2 * 16 + (l >> 5) * 8;
        const int n    = l & 31;
        bf16x8 o = { (bf16_t)tile[krow + 0][n], (bf16_t)tile[krow + 1][n],
                     (bf16_t)tile[krow + 2][n], (bf16_t)tile[krow + 3][n],
                     (bf16_t)tile[krow + 4][n], (bf16_t)tile[krow + 5][n],
                     (bf16_t)tile[krow + 6][n], (bf16_t)tile[krow + 7][n] };
        *(bf16x8*)(Wswz + (size_t)e * 81920 + base
                   + ((size_t)(nt * KC + kt * 4 + kc2) * 64 + l) * 8) = o;
    }
}

// ---- prep: x -> frag-linear bf16 + gating softmax -> gT[e][b] ----
__global__ void prep_xg(const float* __restrict__ x, const float* __restrict__ Wg,
                        const float* __restrict__ bg,
                        bf16_t* __restrict__ xswz, float* __restrict__ gT)
{
    const int bt  = blockIdx.x;     // 512 tiles of 32 rows
    const int tid = threadIdx.x;    // 256
    const int r   = tid >> 3;       // 32 rows
    const int seg = tid & 7;        // 8 segments of 32 k

    // x swizzle
    {
        const float* xp = x + ((size_t)bt * 32 + r) * IN_DIM + seg * 32;
        float xv[32];
#pragma unroll
        for (int i = 0; i < 8; i++) *(float4*)&xv[i * 4] = *(const float4*)(xp + i * 4);
#pragma unroll
        for (int kk = 0; kk < 4; kk++) {
            const int kc = seg * 2 + (kk >> 1);
            const int h  = kk & 1;
            const float* vv = &xv[(kk >> 1) * 16 + h * 8];
            bf16x8 o = { (bf16_t)vv[0], (bf16_t)vv[1], (bf16_t)vv[2], (bf16_t)vv[3],
                         (bf16_t)vv[4], (bf16_t)vv[5], (bf16_t)vv[6], (bf16_t)vv[7] };
            *(bf16x8*)(xswz + ((size_t)(bt * 16 + kc) * 64 + h * 32 + r) * 8) = o;
        }
    }
    // gating: thread computes 4 experts for its row; reduce over the 8-thread group
    {
        const float* xr = x + ((size_t)bt * 32 + r) * IN_DIM;
        float acc[4];
#pragma unroll
        for (int j = 0; j < 4; j++) acc[j] = bg[seg * 4 + j];
        for (int k = 0; k < IN_DIM; k++) {
            const float xk = xr[k];
#pragma unroll
            for (int j = 0; j < 4; j++) acc[j] = fmaf(xk, Wg[k * 32 + seg * 4 + j], acc[j]);
        }
        float mx = fmaxf(fmaxf(acc[0], acc[1]), fmaxf(acc[2], acc[3]));
#pragma unroll
        for (int off = 1; off < 8; off <<= 1) mx = fmaxf(mx, __shfl_xor(mx, off));
        float ex[4], sm = 0.f;
#pragma unroll
        for (int j = 0; j < 4; j++) { ex[j] = __expf(acc[j] - mx); sm += ex[j]; }
#pragma unroll
        for (int off = 1; off < 8; off <<= 1) sm += __shfl_xor(sm, off);
        const float rs = 1.f / sm;
#pragma unroll
        for (int j = 0; j < 4; j++)
            gT[(size_t)(seg * 4 + j) * BB + bt * 32 + r] = ex[j] * rs;
    }
}

// ---- relayout: D-tile (f32x16, +bias, relu) -> 2 B-operand bf16x8 chunks ----
// D: col=lane&31, row=(reg&3)+8*(reg>>2)+4*half. B chunk c needs k'=16c+8*half+j.
template<bool RELU>
__device__ __forceinline__ void relayout2(const f32x16& acc, const float* bs32,
                                          int half, bf16x8* out)
{
    float v[16];
    const f32x4* bq = (const f32x4*)(bs32 + half * 16);
#pragma unroll
    for (int qq = 0; qq < 4; qq++) {
        const f32x4 b4v = bq[qq];
#pragma unroll
        for (int i = 0; i < 4; i++) {
            float t = acc[qq * 4 + i] + b4v[i];
            v[qq * 4 + i] = RELU ? fmaxf(t, 0.f) : t;
        }
    }
#pragma unroll
    for (int c = 0; c < 2; c++) {
        float own[4], snd[4], rcv[4];
#pragma unroll
        for (int d = 0; d < 4; d++) {
            own[d] = half ? v[8 * c + 4 + d] : v[8 * c + d];
            snd[d] = half ? v[8 * c + d]     : v[8 * c + 4 + d];
        }
#pragma unroll
        for (int d = 0; d < 4; d++) rcv[d] = __shfl_xor(snd[d], 32, 64);
        float lo[4], hi[4];
#pragma unroll
        for (int d = 0; d < 4; d++) {
            lo[d] = half ? rcv[d] : own[d];
            hi[d] = half ? own[d] : rcv[d];
        }
        out[c] = (bf16x8){ (bf16_t)lo[0], (bf16_t)lo[1], (bf16_t)lo[2], (bf16_t)lo[3],
                           (bf16_t)hi[0], (bf16_t)hi[1], (bf16_t)hi[2], (bf16_t)hi[3] };
    }
}

// ---- one register-resident layer: NT n-tiles, KS k-chunks; weights stream from wp ----
template<int NT, int KS, bool RELU>
__device__ __forceinline__ const bf16_t* layerR(const bf16_t* __restrict__ wp,
                                                const float* __restrict__ bsc,
                                                const bf16x8* __restrict__ bin,
                                                bf16x8* __restrict__ bout,
                                                int lane, int half)
{
#pragma unroll
    for (int nt = 0; nt < NT; nt++) {
        f32x16 acc;
#pragma unroll
        for (int r = 0; r < 16; r++) acc[r] = 0.f;
#pragma unroll
        for (int kc = 0; kc < KS; kc++) {
            const bf16x8 wf = *(const bf16x8*)(wp + ((size_t)(nt * KS + kc) * 64 + lane) * 8);
            acc = __builtin_amdgcn_mfma_f32_32x32x16_bf16(wf, bin[kc], acc, 0, 0, 0);
        }
        relayout2<RELU>(acc, bsc + nt * 32, half, &bout[2 * nt]);
    }
    return wp + (size_t)NT * KS * 512;
}

// ---- main: zero per-layer barriers; block = 2 row-tiles x 4 expert-groups ----
// Wave: 32 rows, 8 experts, whole 5-layer chain in registers. In-LDS expert combine.
__global__ __launch_bounds__(512, 2) void moe_main(
    const bf16_t* __restrict__ Wswz, const float* __restrict__ bswz,
    const bf16_t* __restrict__ xswz, const float* __restrict__ gT,
    float* __restrict__ out)
{
    __shared__ float red[2][32][132];   // [tile][batch row][feature], 33792 B

    const int tid    = threadIdx.x;
    const int wave   = tid >> 6;
    const int lane   = tid & 63;
    const int lane31 = lane & 31;
    const int half   = lane >> 5;
    const int tl     = wave & 1;        // tile within block
    const int grp    = wave >> 1;       // expert group 0..3
    const int bt     = blockIdx.x * 2 + tl;   // 0..511
    const int b0w    = bt * 32;

    float oacc[4][16];
#pragma unroll
    for (int nt = 0; nt < 4; nt++)
#pragma unroll
        for (int r = 0; r < 16; r++) oacc[nt][r] = 0.f;

    const bf16_t* xs = xswz + (size_t)bt * 8192;

    for (int ei = 0; ei < 8; ei++) {
        const int e = grp * 8 + ei;
        const bf16_t* wp = Wswz + (size_t)e * 81920;
        const float*  bs = bswz + (size_t)e * 640;

        // x B-frags: reload per expert (L1-hot 8KB slab) to cap live VGPRs
        bf16x8 xf[16];
#pragma unroll
        for (int kc = 0; kc < 16; kc++)
            xf[kc] = *(const bf16x8*)(xs + ((size_t)kc * 64 + lane) * 8);

        bf16x8 h1B[4], h2B[16], h3B[8], h4B[4];
        wp = layerR<2, 16, true>(wp, bs,           xf,  h1B, lane, half);   // L1
        wp = layerR<8, 4,  true>(wp, bs + 2 * 32,  h1B, h2B, lane, half);   // L2
        wp = layerR<4, 16, true>(wp, bs + 10 * 32, h2B, h3B, lane, half);   // L3
        wp = layerR<2, 8,  true>(wp, bs + 14 * 32, h3B, h4B, lane, half);   // L4

        // L5: gated accumulate (no relayout)
        const float gv = gT[(size_t)e * BB + b0w + lane31];
#pragma unroll
        for (int nt = 0; nt < 4; nt++) {
            f32x16 acc;
#pragma unroll
            for (int r = 0; r < 16; r++) acc[r] = 0.f;
#pragma unroll
            for (int kc = 0; kc < 4; kc++) {
                const bf16x8 wf = *(const bf16x8*)(wp + ((size_t)(nt * 4 + kc) * 64 + lane) * 8);
                acc = __builtin_amdgcn_mfma_f32_32x32x16_bf16(wf, h4B[kc], acc, 0, 0, 0);
            }
            const f32x4* bq = (const f32x4*)(bs + (16 + nt) * 32 + half * 16);
#pragma unroll
            for (int qq = 0; qq < 4; qq++) {
                const f32x4 b4v = bq[qq];
#pragma unroll
                for (int i = 0; i < 4; i++)
                    oacc[nt][qq * 4 + i] += gv * (acc[qq * 4 + i] + b4v[i]);
            }
        }
    }

    // ---- in-LDS combine over the 4 expert groups ----
    if (grp == 0) {
#pragma unroll
        for (int nt = 0; nt < 4; nt++)
#pragma unroll
            for (int r = 0; r < 16; r++) {
                const int f = nt * 32 + (r & 3) + 8 * (r >> 2) + 4 * half;
                red[tl][lane31][f] = oacc[nt][r];
            }
    }
    __syncthreads();
    if (grp != 0) {
#pragma unroll
        for (int nt = 0; nt < 4; nt++)
#pragma unroll
            for (int r = 0; r < 16; r++) {
                const int f = nt * 32 + (r & 3) + 8 * (r >> 2) + 4 * half;
                atomicAdd(&red[tl][lane31][f], oacc[nt][r]);
            }
    }
    __syncthreads();

    // ---- cooperative coalesced store ----
#pragma unroll
    for (int i = 0; i < 4; i++) {
        const int lin = i * 512 + tid;       // 0..2047 float4s
        const int t   = lin >> 10;
        const int rem = lin & 1023;
        const int row = rem >> 5;
        const int q4  = rem & 31;
        const float* rp = &red[t][row][q4 * 4];
        float4 v = { rp[0], rp[1], rp[2], rp[3] };
        *(float4*)(out + ((size_t)(blockIdx.x * 2 + t) * 32 + row) * NOUT + q4 * 4) = v;
    }
}

extern "C" void kernel_launch(void* const* d_in, const int* in_sizes, int n_in,
                              void* d_out, int out_size, void* d_ws, size_t ws_size,
                              hipStream_t stream)
{
    (void)in_sizes; (void)n_in; (void)out_size; (void)ws_size;
    const float* x  = (const float*)d_in[0];
    const float* Wg = (const float*)d_in[1];
    const float* bg = (const float*)d_in[2];
    const float* W1 = (const float*)d_in[3];
    const float* b1 = (const float*)d_in[4];
    const float* W2 = (const float*)d_in[5];
    const float* b2 = (const float*)d_in[6];
    const float* W3 = (const float*)d_in[7];
    const float* b3 = (const float*)d_in[8];
    const float* W4 = (const float*)d_in[9];
    const float* b4 = (const float*)d_in[10];
    const float* W5 = (const float*)d_in[11];
    const float* b5 = (const float*)d_in[12];

    char* ws = (char*)d_ws;
    bf16_t* Wswz = (bf16_t*)(ws + OFF_WS);
    float*  bswz = (float*)(ws + OFF_BS);
    bf16_t* xswz = (bf16_t*)(ws + OFF_XS);
    float*  gT   = (float*)(ws + OFF_GT);
    float*  out  = (float*)d_out;

    prep_w<<<dim3(NE * 41), dim3(256), 0, stream>>>(W1, W2, W3, W4, W5,
                                                    b1, b2, b3, b4, b5, Wswz, bswz);
    prep_xg<<<dim3(512), dim3(256), 0, stream>>>(x, Wg, bg, xswz, gT);
    moe_main<<<dim3(256), dim3(512), 0, stream>>>(Wswz, bswz, xswz, gT, out);
}